// Round 3
// baseline (267.717 us; speedup 1.0000x reference)
//
#include <hip/hip_runtime.h>
#include <stdint.h>

#define NROWS 4096
#define DIM   128
#define KB    8
#define NS    7            // K-1 negatives per anchor
#define TCH   16           // candidate chunks (256 cands each)
#define HALF_CNT 58720256u // (4096*7*4096)/2

typedef __bf16 v8bf __attribute__((ext_vector_type(8)));
typedef float  v4f  __attribute__((ext_vector_type(4)));

__device__ __forceinline__ uint32_t rotl32(uint32_t x, int r) {
    return (x << r) | (x >> (32 - r));
}

// JAX threefry2x32, key = [0, 42], 20 rounds. (c0,c1)=(L, L+HALF_CNT):
// o0 = bits for flat index L, o1 = bits for flat index L+HALF_CNT.
__device__ __forceinline__ void threefry2x32(uint32_t c0, uint32_t c1,
                                             uint32_t& o0, uint32_t& o1) {
    const uint32_t ks0 = 0u;
    const uint32_t ks1 = 42u;
    const uint32_t ks2 = 0x1BD11BDAu ^ ks0 ^ ks1;
    uint32_t x0 = c0 + ks0;
    uint32_t x1 = c1 + ks1;
#define TF_R(r) { x0 += x1; x1 = rotl32(x1, r); x1 ^= x0; }
    TF_R(13) TF_R(15) TF_R(26) TF_R(6)
    x0 += ks1; x1 += ks2 + 1u;
    TF_R(17) TF_R(29) TF_R(16) TF_R(24)
    x0 += ks2; x1 += ks0 + 2u;
    TF_R(13) TF_R(15) TF_R(26) TF_R(6)
    x0 += ks0; x1 += ks1 + 3u;
    TF_R(17) TF_R(29) TF_R(16) TF_R(24)
    x0 += ks1; x1 += ks2 + 4u;
    TF_R(13) TF_R(15) TF_R(26) TF_R(6)
    x0 += ks2; x1 += ks0 + 5u;
#undef TF_R
    o0 = x0; o1 = x1;
}

// gumbel = -ln(-ln(u)), u = f + tiny, via native v_log_f32 (log2)
__device__ __forceinline__ float gumbel_of(uint32_t b) {
    float f = __uint_as_float((b >> 9) | 0x3f800000u) - 1.0f;   // [0,1)
    float u = f + 1.17549435e-38f;
    float l1 = __log2f(u);                    // <= 0
    float inner = -0.69314718055994531f * l1; // -ln(u) >= 0
    float l2 = __log2f(inner);
    return -0.69314718055994531f * l2;
}

// ---------------- kernel 1: normalize -> bf16 hi/lo planes + sq -----------
__global__ void knorm(const float* __restrict__ x, __bf16* __restrict__ xh,
                      __bf16* __restrict__ xl, float* __restrict__ sqv) {
    const int i = blockIdx.x;
    const int t = threadIdx.x;  // 64 threads, 2 elems each
    float2 v = ((const float2*)(x + (size_t)i * DIM))[t];
    float s = v.x * v.x + v.y * v.y;
#pragma unroll
    for (int m = 32; m > 0; m >>= 1) s += __shfl_xor(s, m, 64);
    float norm = sqrtf(s) + 1e-5f;
    float ox = v.x / norm, oy = v.y / norm;
    __bf16 hx = (__bf16)ox, hy = (__bf16)oy;
    float lx = ox - (float)hx, ly = oy - (float)hy;
    union { __bf16 b[2]; uint32_t u; } ph, pl;
    ph.b[0] = hx; ph.b[1] = hy;
    pl.b[0] = (__bf16)lx; pl.b[1] = (__bf16)ly;
    ((uint32_t*)xh)[i * 64 + t] = ph.u;
    ((uint32_t*)xl)[i * 64 + t] = pl.u;
    float s2 = ox * ox + oy * oy;
#pragma unroll
    for (int m = 32; m > 0; m >>= 1) s2 += __shfl_xor(s2, m, 64);
    if (t == 0) sqv[i] = s2;
}

// ---------------- kernel 2: MFMA dots + fused gumbel argmax ---------------
// 256-thread blocks = 4 independent waves, each owning one candidate chunk.
// Wave = 16 anchor-rows (8 (i,i+2048) pairs) x 256 cands. No LDS, no barriers.
// grid = (TCH/4, 256 row-groups).
__global__ __launch_bounds__(256, 4) void ksample(
        const __bf16* __restrict__ xh, const __bf16* __restrict__ xl,
        const float* __restrict__ sqv,
        float* __restrict__ pV, int* __restrict__ pI) {
    const int lane  = threadIdx.x & 63;
    const int chunk = (blockIdx.x << 2) + (threadIdx.x >> 6);   // 0..15
    const int grp   = blockIdx.y;   // 0..255
    const int rlo = lane & 15;
    const int khi = lane >> 4;

    // A fragments: frag-row rlo -> anchor grp*8 + (rlo>>1) + (rlo&1)*2048
    const int afr = grp * 8 + (rlo >> 1) + ((rlo & 1) << 11);
    v8bf ah[4], al[4];
#pragma unroll
    for (int ks = 0; ks < 4; ++ks) {
        const size_t off = (size_t)afr * DIM + ks * 32 + khi * 8;
        ah[ks] = *(const v8bf*)(xh + off);
        al[ks] = *(const v8bf*)(xl + off);
    }

    // C rows for this lane: r = khi*4+q -> anchor base + (q>>1) + (q&1)*2048
    const int base = grp * 8 + khi * 2;
    float sqA[4];
    sqA[0] = sqv[base];
    sqA[1] = sqv[base + 2048];
    sqA[2] = sqv[base + 1];
    sqA[3] = sqv[base + 2049];
    const uint32_t P0 = (uint32_t)base;
    const uint32_t P1 = (uint32_t)(base + 1);

    float bestV[4][NS];
    int   bestI[4][NS];
#pragma unroll
    for (int q = 0; q < 4; ++q)
#pragma unroll
        for (int j = 0; j < NS; ++j) { bestV[q][j] = -INFINITY; bestI[q][j] = 0x7FFFFFFF; }

    const int tcol0 = chunk * 256 + rlo;

    // prefetch cg=0 B-fragments + sq
    v8bf bhn[4], bln[4];
    float sqn;
    {
        const size_t boff = (size_t)tcol0 * DIM + khi * 8;
#pragma unroll
        for (int ks = 0; ks < 4; ++ks) {
            bhn[ks] = *(const v8bf*)(xh + boff + ks * 32);
            bln[ks] = *(const v8bf*)(xl + boff + ks * 32);
        }
        sqn = sqv[tcol0];
    }

#pragma unroll 1
    for (int cg = 0; cg < 16; ++cg) {
        // consume prefetched regs
        v8bf bhc[4], blc[4];
#pragma unroll
        for (int ks = 0; ks < 4; ++ks) { bhc[ks] = bhn[ks]; blc[ks] = bln[ks]; }
        const float sqB = sqn;
        const int tcol = tcol0 + cg * 16;

        // issue next-cg loads (hide L2 latency under this cg's j-loop)
        if (cg < 15) {
            const size_t boff = (size_t)(tcol + 16) * DIM + khi * 8;
#pragma unroll
            for (int ks = 0; ks < 4; ++ks) {
                bhn[ks] = *(const v8bf*)(xh + boff + ks * 32);
                bln[ks] = *(const v8bf*)(xl + boff + ks * 32);
            }
            sqn = sqv[tcol + 16];
        }

        // split-precision dots: hi*hi + hi*lo + lo*hi (lo*lo ~ 2^-18, dropped)
        v4f acc1 = {0.f, 0.f, 0.f, 0.f};
        v4f acc2 = {0.f, 0.f, 0.f, 0.f};
        v4f acc3 = {0.f, 0.f, 0.f, 0.f};
#pragma unroll
        for (int ks = 0; ks < 4; ++ks) {
            acc1 = __builtin_amdgcn_mfma_f32_16x16x32_bf16(ah[ks], bhc[ks], acc1, 0, 0, 0);
            acc2 = __builtin_amdgcn_mfma_f32_16x16x32_bf16(ah[ks], blc[ks], acc2, 0, 0, 0);
            acc3 = __builtin_amdgcn_mfma_f32_16x16x32_bf16(al[ks], bhc[ks], acc3, 0, 0, 0);
        }

        const int tBlk = tcol >> 3;
        const bool bd0 = (tBlk != grp);          // vs h=0 anchors (block = grp)
        const bool bd1 = (tBlk != grp + 256);    // vs h=1 anchors

        float lg[4];
#pragma unroll
        for (int q = 0; q < 4; ++q) {
            float dot = acc1[q] + acc2[q] + acc3[q];
            float d2  = fmaf(-2.0f, dot, sqA[q] + sqB);
            float l1  = __log2f(d2);                    // -126*ln(d) = -63*ln(d2)
            float t2  = fmaf(-0.25f, d2, 1.0f);
            float l2  = __log2f(t2);
            float lw  = fmaf(-43.66827237527655f, l1, -43.32169878499658f * l2);
            bool incl = (d2 < 1.96f) && ((q & 1) ? bd1 : bd0);
            lg[q] = incl ? lw : -INFINITY;
        }

        const uint32_t tB = (uint32_t)tcol;
#pragma unroll
        for (int j = 0; j < NS; ++j) {
            uint32_t L0 = ((P0 * 7u + (uint32_t)j) << 12) + tB;
            uint32_t L1 = ((P1 * 7u + (uint32_t)j) << 12) + tB;
            uint32_t o0, o1, o2, o3;
            threefry2x32(L0, L0 + HALF_CNT, o0, o1);
            threefry2x32(L1, L1 + HALF_CNT, o2, o3);
            float v0 = lg[0] + gumbel_of(o0);
            float v1 = lg[1] + gumbel_of(o1);
            float v2 = lg[2] + gumbel_of(o2);
            float v3 = lg[3] + gumbel_of(o3);
            if (v0 > bestV[0][j]) { bestV[0][j] = v0; bestI[0][j] = tcol; }
            if (v1 > bestV[1][j]) { bestV[1][j] = v1; bestI[1][j] = tcol; }
            if (v2 > bestV[2][j]) { bestV[2][j] = v2; bestI[2][j] = tcol; }
            if (v3 > bestV[3][j]) { bestV[3][j] = v3; bestI[3][j] = tcol; }
        }
    }

    // reduce across the 16 lanes (rlo) sharing each row set; write partials
#pragma unroll
    for (int q = 0; q < 4; ++q) {
        const int a = base + (q >> 1) + ((q & 1) << 11);
#pragma unroll
        for (int j = 0; j < NS; ++j) {
            float v = bestV[q][j];
            int idx = bestI[q][j];
#pragma unroll
            for (int m = 1; m < 16; m <<= 1) {
                float v2 = __shfl_xor(v, m, 16);
                int   i2 = __shfl_xor(idx, m, 16);
                if (v2 > v || (v2 == v && i2 < idx)) { v = v2; idx = i2; }
            }
            if (rlo == 0) {
                size_t s = ((size_t)a * NS + j) * TCH + chunk;
                pV[s] = v;
                pI[s] = idx;
            }
        }
    }
}

// ---------------- kernel 3: combine chunk partials -> n_idx ---------------
// bv == -inf  <=>  no included candidate for row (== reference's invalid row)
__global__ void kcombine(const float* __restrict__ pV, const int* __restrict__ pI,
                         int* __restrict__ nidx) {
    int s = blockIdx.x * 256 + threadIdx.x;
    if (s >= NROWS * NS) return;
    float bv = -INFINITY;
    int bi = 0x7FFFFFFF;
#pragma unroll
    for (int c = 0; c < TCH; ++c) {
        float v = pV[(size_t)s * TCH + c];
        int idx = pI[(size_t)s * TCH + c];
        if (v > bv || (v == bv && idx < bi)) { bv = v; bi = idx; }
    }
    nidx[s] = (bv == -INFINITY) ? -1 : bi;
}

// ---------------- kernel 4: uniform fallback for invalid rows -------------
__global__ void kfixup(int* __restrict__ nidx) {
    const int i = blockIdx.x;
    if (nidx[(size_t)i * NS] >= 0) return;   // normal case: immediate exit
    const int lane = threadIdx.x;            // 64
    for (int j = 0; j < NS; ++j) {
        float bv = -INFINITY;
        int bi = 0x7FFFFFFF;
        for (int t = lane; t < NROWS; t += 64) {
            uint32_t o0, o1;
            float g;
            if (i < 2048) {
                uint32_t L = (((uint32_t)(i * NS + j)) << 12) + (uint32_t)t;
                threefry2x32(L, L + HALF_CNT, o0, o1);
                g = gumbel_of(o0);
            } else {
                uint32_t L = (((uint32_t)((i - 2048) * NS + j)) << 12) + (uint32_t)t;
                threefry2x32(L, L + HALF_CNT, o0, o1);
                g = gumbel_of(o1);
            }
            if (g > bv) { bv = g; bi = t; }
        }
#pragma unroll
        for (int m = 1; m < 64; m <<= 1) {
            float v2 = __shfl_xor(bv, m, 64);
            int   i2 = __shfl_xor(bi, m, 64);
            if (v2 > bv || (v2 == bv && i2 < bi)) { bv = v2; bi = i2; }
        }
        if (lane == 0) nidx[i * NS + j] = bi;
    }
}

// ---------------- kernel 5: triplet losses --------------------------------
__global__ void kloss(const float* __restrict__ x, const int* __restrict__ nidx,
                      float* __restrict__ loss) {
    int s = blockIdx.x * 256 + threadIdx.x;
    if (s >= NROWS * NS) return;
    int i = s / NS, j = s - i * NS;
    int r = i & (KB - 1), blk = i >> 3;
    int po = (j < r) ? j : j + 1;
    int p = blk * KB + po;
    int n = nidx[s] & (NROWS - 1);      // defensive clamp (no-op when correct)
    const float4* A  = (const float4*)(x + (size_t)i * DIM);
    const float4* P  = (const float4*)(x + (size_t)p * DIM);
    const float4* Ng = (const float4*)(x + (size_t)n * DIM);
    float sap = 0.0f, san = 0.0f;
#pragma unroll 8
    for (int k = 0; k < DIM / 4; ++k) {
        float4 a = A[k], pv = P[k], nv = Ng[k];
        float d;
        d = a.x - pv.x + 1e-6f; sap += d * d;
        d = a.y - pv.y + 1e-6f; sap += d * d;
        d = a.z - pv.z + 1e-6f; sap += d * d;
        d = a.w - pv.w + 1e-6f; sap += d * d;
        d = a.x - nv.x + 1e-6f; san += d * d;
        d = a.y - nv.y + 1e-6f; san += d * d;
        d = a.z - nv.z + 1e-6f; san += d * d;
        d = a.w - nv.w + 1e-6f; san += d * d;
    }
    loss[s] = fmaxf(sqrtf(sap) - sqrtf(san) + 1.0f, 0.0f);
}

// ---------------- kernel 6: mean ------------------------------------------
__global__ void kreduce(const float* __restrict__ loss, float* __restrict__ out) {
    __shared__ float part[4];
    const int tid = threadIdx.x;
    float sum = 0.0f;
    for (int s = tid; s < NROWS * NS; s += 256) sum += loss[s];
#pragma unroll
    for (int m = 32; m > 0; m >>= 1) sum += __shfl_xor(sum, m, 64);
    if ((tid & 63) == 0) part[tid >> 6] = sum;
    __syncthreads();
    if (tid == 0) out[0] = (part[0] + part[1] + part[2] + part[3]) / 28672.0f;
}

extern "C" void kernel_launch(void* const* d_in, const int* in_sizes, int n_in,
                              void* d_out, int out_size, void* d_ws, size_t ws_size,
                              hipStream_t stream) {
    const float* x = (const float*)d_in[0];
    float* out = (float*)d_out;

    __bf16* xh   = (__bf16*)d_ws;                     // 4096*128 bf16
    __bf16* xl   = xh + NROWS * DIM;                  // 4096*128 bf16
    float*  sqv  = (float*)(xl + NROWS * DIM);        // 4096
    float*  pV   = sqv + NROWS;                       // 4096*7*16
    int*    pI   = (int*)(pV + NROWS * NS * TCH);     // 4096*7*16
    int*    nidx = pI + NROWS * NS * TCH;             // 4096*7
    float*  loss = (float*)(nidx + NROWS * NS);       // 4096*7

    knorm<<<NROWS, 64, 0, stream>>>(x, xh, xl, sqv);
    ksample<<<dim3(TCH / 4, 256), 256, 0, stream>>>(xh, xl, sqv, pV, pI);
    kcombine<<<(NROWS * NS + 255) / 256, 256, 0, stream>>>(pV, pI, nidx);
    kfixup<<<NROWS, 64, 0, stream>>>(nidx);
    kloss<<<(NROWS * NS + 255) / 256, 256, 0, stream>>>(x, nidx, loss);
    kreduce<<<1, 256, 0, stream>>>(loss, out);
}

// Round 4
// 222.099 us; speedup vs baseline: 1.2054x; 1.2054x over previous
//
#include <hip/hip_runtime.h>
#include <stdint.h>

#define NROWS 4096
#define DIM   128
#define KB    8
#define NS    7            // K-1 negatives per anchor
#define TCH   16           // candidate chunks (256 cands each)
#define HALF_CNT 58720256u // (4096*7*4096)/2

typedef __bf16 v8bf __attribute__((ext_vector_type(8)));
typedef float  v4f  __attribute__((ext_vector_type(4)));

__device__ __forceinline__ uint32_t rotl32(uint32_t x, int r) {
    return (x << r) | (x >> (32 - r));
}

// JAX threefry2x32, key = [0, 42], 20 rounds. (c0,c1)=(L, L+HALF_CNT):
// o0 = bits for flat index L, o1 = bits for flat index L+HALF_CNT.
__device__ __forceinline__ void threefry2x32(uint32_t c0, uint32_t c1,
                                             uint32_t& o0, uint32_t& o1) {
    const uint32_t ks0 = 0u;
    const uint32_t ks1 = 42u;
    const uint32_t ks2 = 0x1BD11BDAu ^ ks0 ^ ks1;
    uint32_t x0 = c0 + ks0;
    uint32_t x1 = c1 + ks1;
#define TF_R(r) { x0 += x1; x1 = rotl32(x1, r); x1 ^= x0; }
    TF_R(13) TF_R(15) TF_R(26) TF_R(6)
    x0 += ks1; x1 += ks2 + 1u;
    TF_R(17) TF_R(29) TF_R(16) TF_R(24)
    x0 += ks2; x1 += ks0 + 2u;
    TF_R(13) TF_R(15) TF_R(26) TF_R(6)
    x0 += ks0; x1 += ks1 + 3u;
    TF_R(17) TF_R(29) TF_R(16) TF_R(24)
    x0 += ks1; x1 += ks2 + 4u;
    TF_R(13) TF_R(15) TF_R(26) TF_R(6)
    x0 += ks2; x1 += ks0 + 5u;
#undef TF_R
    o0 = x0; o1 = x1;
}

// gumbel = -ln(-ln(u)), u = f + tiny, via native v_log_f32 (log2)
__device__ __forceinline__ float gumbel_of(uint32_t b) {
    float f = __uint_as_float((b >> 9) | 0x3f800000u) - 1.0f;   // [0,1)
    float u = f + 1.17549435e-38f;
    float l1 = __log2f(u);                    // <= 0
    float inner = -0.69314718055994531f * l1; // -ln(u) >= 0
    float l2 = __log2f(inner);
    return -0.69314718055994531f * l2;
}

// ---------------- kernel 1: normalize -> bf16 hi/lo planes + sq -----------
__global__ void knorm(const float* __restrict__ x, __bf16* __restrict__ xh,
                      __bf16* __restrict__ xl, float* __restrict__ sqv) {
    const int i = blockIdx.x;
    const int t = threadIdx.x;  // 64 threads, 2 elems each
    float2 v = ((const float2*)(x + (size_t)i * DIM))[t];
    float s = v.x * v.x + v.y * v.y;
#pragma unroll
    for (int m = 32; m > 0; m >>= 1) s += __shfl_xor(s, m, 64);
    float norm = sqrtf(s) + 1e-5f;
    float ox = v.x / norm, oy = v.y / norm;
    __bf16 hx = (__bf16)ox, hy = (__bf16)oy;
    float lx = ox - (float)hx, ly = oy - (float)hy;
    union { __bf16 b[2]; uint32_t u; } ph, pl;
    ph.b[0] = hx; ph.b[1] = hy;
    pl.b[0] = (__bf16)lx; pl.b[1] = (__bf16)ly;
    ((uint32_t*)xh)[i * 64 + t] = ph.u;
    ((uint32_t*)xl)[i * 64 + t] = pl.u;
    float s2 = ox * ox + oy * oy;
#pragma unroll
    for (int m = 32; m > 0; m >>= 1) s2 += __shfl_xor(s2, m, 64);
    if (t == 0) sqv[i] = s2;
}

// ---------------- kernel 2: MFMA dots + fused gumbel argmax ---------------
// 256-thread blocks = 4 independent waves, each owning one candidate chunk.
// Wave = 16 anchor-rows (8 (i,i+2048) pairs) x 256 cands. No LDS, no barriers.
// grid = (TCH/4, 256 row-groups). Winning index within a lane is encoded as
// the 4-bit cg loop counter (idx = tcol0 + cg*16): 7 samples pack into one
// u32 per accumulator row -> 4 regs of index state instead of 28.
__global__ __launch_bounds__(256, 2) void ksample(
        const __bf16* __restrict__ xh, const __bf16* __restrict__ xl,
        const float* __restrict__ sqv,
        float* __restrict__ pV, int* __restrict__ pI) {
    const int lane  = threadIdx.x & 63;
    const int chunk = (blockIdx.x << 2) + (threadIdx.x >> 6);   // 0..15
    const int grp   = blockIdx.y;   // 0..255
    const int rlo = lane & 15;
    const int khi = lane >> 4;

    // A fragments: frag-row rlo -> anchor grp*8 + (rlo>>1) + (rlo&1)*2048
    const int afr = grp * 8 + (rlo >> 1) + ((rlo & 1) << 11);
    v8bf ah[4], al[4];
#pragma unroll
    for (int ks = 0; ks < 4; ++ks) {
        const size_t off = (size_t)afr * DIM + ks * 32 + khi * 8;
        ah[ks] = *(const v8bf*)(xh + off);
        al[ks] = *(const v8bf*)(xl + off);
    }

    // C rows for this lane: r = khi*4+q -> anchor base + (q>>1) + (q&1)*2048
    const int base = grp * 8 + khi * 2;
    float sqA[4];
    sqA[0] = sqv[base];
    sqA[1] = sqv[base + 2048];
    sqA[2] = sqv[base + 1];
    sqA[3] = sqv[base + 2049];
    const uint32_t P0 = (uint32_t)base;
    const uint32_t P1 = (uint32_t)(base + 1);

    float    bestV[4][NS];
    uint32_t bestP[4];          // packed 4-bit cg per sample slot
#pragma unroll
    for (int q = 0; q < 4; ++q) {
        bestP[q] = 0u;
#pragma unroll
        for (int j = 0; j < NS; ++j) bestV[q][j] = -INFINITY;
    }

    const int tcol0 = chunk * 256 + rlo;

    // prefetch cg=0 B-fragments + sq
    v8bf bhn[4], bln[4];
    float sqn;
    {
        const size_t boff = (size_t)tcol0 * DIM + khi * 8;
#pragma unroll
        for (int ks = 0; ks < 4; ++ks) {
            bhn[ks] = *(const v8bf*)(xh + boff + ks * 32);
            bln[ks] = *(const v8bf*)(xl + boff + ks * 32);
        }
        sqn = sqv[tcol0];
    }

#pragma unroll 1
    for (int cg = 0; cg < 16; ++cg) {
        // consume prefetched regs
        v8bf bhc[4], blc[4];
#pragma unroll
        for (int ks = 0; ks < 4; ++ks) { bhc[ks] = bhn[ks]; blc[ks] = bln[ks]; }
        const float sqB = sqn;
        const int tcol = tcol0 + cg * 16;

        // issue next-cg loads (hide L2 latency under this cg's j-loop)
        if (cg < 15) {
            const size_t boff = (size_t)(tcol + 16) * DIM + khi * 8;
#pragma unroll
            for (int ks = 0; ks < 4; ++ks) {
                bhn[ks] = *(const v8bf*)(xh + boff + ks * 32);
                bln[ks] = *(const v8bf*)(xl + boff + ks * 32);
            }
            sqn = sqv[tcol + 16];
        }

        // split-precision dots: hi*hi + hi*lo + lo*hi (lo*lo ~ 2^-18, dropped)
        v4f acc1 = {0.f, 0.f, 0.f, 0.f};
        v4f acc2 = {0.f, 0.f, 0.f, 0.f};
        v4f acc3 = {0.f, 0.f, 0.f, 0.f};
#pragma unroll
        for (int ks = 0; ks < 4; ++ks) {
            acc1 = __builtin_amdgcn_mfma_f32_16x16x32_bf16(ah[ks], bhc[ks], acc1, 0, 0, 0);
            acc2 = __builtin_amdgcn_mfma_f32_16x16x32_bf16(ah[ks], blc[ks], acc2, 0, 0, 0);
            acc3 = __builtin_amdgcn_mfma_f32_16x16x32_bf16(al[ks], bhc[ks], acc3, 0, 0, 0);
        }

        const int tBlk = tcol >> 3;
        const bool bd0 = (tBlk != grp);          // vs h=0 anchors (block = grp)
        const bool bd1 = (tBlk != grp + 256);    // vs h=1 anchors

        float lg[4];
#pragma unroll
        for (int q = 0; q < 4; ++q) {
            float dot = acc1[q] + acc2[q] + acc3[q];
            float d2  = fmaf(-2.0f, dot, sqA[q] + sqB);
            float l1  = __log2f(d2);                    // -126*ln(d) = -63*ln(d2)
            float t2  = fmaf(-0.25f, d2, 1.0f);
            float l2  = __log2f(t2);
            float lw  = fmaf(-43.66827237527655f, l1, -43.32169878499658f * l2);
            bool incl = (d2 < 1.96f) && ((q & 1) ? bd1 : bd0);
            lg[q] = incl ? lw : -INFINITY;
        }

        const uint32_t tB = (uint32_t)tcol;
#pragma unroll
        for (int j = 0; j < NS; ++j) {
            uint32_t L0 = ((P0 * 7u + (uint32_t)j) << 12) + tB;
            uint32_t L1 = ((P1 * 7u + (uint32_t)j) << 12) + tB;
            uint32_t o0, o1, o2, o3;
            threefry2x32(L0, L0 + HALF_CNT, o0, o1);
            threefry2x32(L1, L1 + HALF_CNT, o2, o3);
            float vv[4];
            vv[0] = lg[0] + gumbel_of(o0);
            vv[1] = lg[1] + gumbel_of(o1);
            vv[2] = lg[2] + gumbel_of(o2);
            vv[3] = lg[3] + gumbel_of(o3);
            const uint32_t keep = ~(0xFu << (4 * j));
            const uint32_t put  = ((uint32_t)cg) << (4 * j);
#pragma unroll
            for (int q = 0; q < 4; ++q) {
                bool gt = vv[q] > bestV[q][j];          // strict >: first-win ties
                uint32_t np = (bestP[q] & keep) | put;  // v_and_or_b32
                bestV[q][j] = gt ? vv[q] : bestV[q][j];
                bestP[q]    = gt ? np : bestP[q];
            }
        }
    }

    // reduce across the 16 lanes (rlo) sharing each row set; write partials
#pragma unroll
    for (int q = 0; q < 4; ++q) {
        const int a = base + (q >> 1) + ((q & 1) << 11);
#pragma unroll
        for (int j = 0; j < NS; ++j) {
            float v = bestV[q][j];
            int idx = tcol0 + (int)((bestP[q] >> (4 * j)) & 0xFu) * 16;
#pragma unroll
            for (int m = 1; m < 16; m <<= 1) {
                float v2 = __shfl_xor(v, m, 16);
                int   i2 = __shfl_xor(idx, m, 16);
                if (v2 > v || (v2 == v && i2 < idx)) { v = v2; idx = i2; }
            }
            if (rlo == 0) {
                size_t s = ((size_t)a * NS + j) * TCH + chunk;
                pV[s] = v;
                pI[s] = idx;
            }
        }
    }
}

// ---------------- kernel 3: combine chunk partials -> n_idx ---------------
// bv == -inf  <=>  no included candidate for row (== reference's invalid row)
__global__ void kcombine(const float* __restrict__ pV, const int* __restrict__ pI,
                         int* __restrict__ nidx) {
    int s = blockIdx.x * 256 + threadIdx.x;
    if (s >= NROWS * NS) return;
    float bv = -INFINITY;
    int bi = 0x7FFFFFFF;
#pragma unroll
    for (int c = 0; c < TCH; ++c) {
        float v = pV[(size_t)s * TCH + c];
        int idx = pI[(size_t)s * TCH + c];
        if (v > bv || (v == bv && idx < bi)) { bv = v; bi = idx; }
    }
    nidx[s] = (bv == -INFINITY) ? -1 : bi;
}

// ---------------- kernel 4: uniform fallback for invalid rows -------------
__global__ void kfixup(int* __restrict__ nidx) {
    const int i = blockIdx.x;
    if (nidx[(size_t)i * NS] >= 0) return;   // normal case: immediate exit
    const int lane = threadIdx.x;            // 64
    for (int j = 0; j < NS; ++j) {
        float bv = -INFINITY;
        int bi = 0x7FFFFFFF;
        for (int t = lane; t < NROWS; t += 64) {
            uint32_t o0, o1;
            float g;
            if (i < 2048) {
                uint32_t L = (((uint32_t)(i * NS + j)) << 12) + (uint32_t)t;
                threefry2x32(L, L + HALF_CNT, o0, o1);
                g = gumbel_of(o0);
            } else {
                uint32_t L = (((uint32_t)((i - 2048) * NS + j)) << 12) + (uint32_t)t;
                threefry2x32(L, L + HALF_CNT, o0, o1);
                g = gumbel_of(o1);
            }
            if (g > bv) { bv = g; bi = t; }
        }
#pragma unroll
        for (int m = 1; m < 64; m <<= 1) {
            float v2 = __shfl_xor(bv, m, 64);
            int   i2 = __shfl_xor(bi, m, 64);
            if (v2 > bv || (v2 == bv && i2 < bi)) { bv = v2; bi = i2; }
        }
        if (lane == 0) nidx[i * NS + j] = bi;
    }
}

// ---------------- kernel 5: triplet losses --------------------------------
__global__ void kloss(const float* __restrict__ x, const int* __restrict__ nidx,
                      float* __restrict__ loss) {
    int s = blockIdx.x * 256 + threadIdx.x;
    if (s >= NROWS * NS) return;
    int i = s / NS, j = s - i * NS;
    int r = i & (KB - 1), blk = i >> 3;
    int po = (j < r) ? j : j + 1;
    int p = blk * KB + po;
    int n = nidx[s] & (NROWS - 1);      // defensive clamp (no-op when correct)
    const float4* A  = (const float4*)(x + (size_t)i * DIM);
    const float4* P  = (const float4*)(x + (size_t)p * DIM);
    const float4* Ng = (const float4*)(x + (size_t)n * DIM);
    float sap = 0.0f, san = 0.0f;
#pragma unroll 8
    for (int k = 0; k < DIM / 4; ++k) {
        float4 a = A[k], pv = P[k], nv = Ng[k];
        float d;
        d = a.x - pv.x + 1e-6f; sap += d * d;
        d = a.y - pv.y + 1e-6f; sap += d * d;
        d = a.z - pv.z + 1e-6f; sap += d * d;
        d = a.w - pv.w + 1e-6f; sap += d * d;
        d = a.x - nv.x + 1e-6f; san += d * d;
        d = a.y - nv.y + 1e-6f; san += d * d;
        d = a.z - nv.z + 1e-6f; san += d * d;
        d = a.w - nv.w + 1e-6f; san += d * d;
    }
    loss[s] = fmaxf(sqrtf(sap) - sqrtf(san) + 1.0f, 0.0f);
}

// ---------------- kernel 6: mean ------------------------------------------
__global__ void kreduce(const float* __restrict__ loss, float* __restrict__ out) {
    __shared__ float part[4];
    const int tid = threadIdx.x;
    float sum = 0.0f;
    for (int s = tid; s < NROWS * NS; s += 256) sum += loss[s];
#pragma unroll
    for (int m = 32; m > 0; m >>= 1) sum += __shfl_xor(sum, m, 64);
    if ((tid & 63) == 0) part[tid >> 6] = sum;
    __syncthreads();
    if (tid == 0) out[0] = (part[0] + part[1] + part[2] + part[3]) / 28672.0f;
}

extern "C" void kernel_launch(void* const* d_in, const int* in_sizes, int n_in,
                              void* d_out, int out_size, void* d_ws, size_t ws_size,
                              hipStream_t stream) {
    const float* x = (const float*)d_in[0];
    float* out = (float*)d_out;

    __bf16* xh   = (__bf16*)d_ws;                     // 4096*128 bf16
    __bf16* xl   = xh + NROWS * DIM;                  // 4096*128 bf16
    float*  sqv  = (float*)(xl + NROWS * DIM);        // 4096
    float*  pV   = sqv + NROWS;                       // 4096*7*16
    int*    pI   = (int*)(pV + NROWS * NS * TCH);     // 4096*7*16
    int*    nidx = pI + NROWS * NS * TCH;             // 4096*7
    float*  loss = (float*)(nidx + NROWS * NS);       // 4096*7

    knorm<<<NROWS, 64, 0, stream>>>(x, xh, xl, sqv);
    ksample<<<dim3(TCH / 4, 256), 256, 0, stream>>>(xh, xl, sqv, pV, pI);
    kcombine<<<(NROWS * NS + 255) / 256, 256, 0, stream>>>(pV, pI, nidx);
    kfixup<<<NROWS, 64, 0, stream>>>(nidx);
    kloss<<<(NROWS * NS + 255) / 256, 256, 0, stream>>>(x, nidx, loss);
    kreduce<<<1, 256, 0, stream>>>(loss, out);
}